// Round 1
// baseline (324.877 us; speedup 1.0000x reference)
//
#include <hip/hip_runtime.h>
#include <math.h>

#define IN_DIM 512
#define OUT_DIM 128

// ---------------------------------------------------------------------------
// GEMM: z[M,128] = x[M,512] @ w[512,128], fp32 vector ALU.
// Tile: BM=128, BN=128 (full N), BK=32. 256 threads, each computes 8x8.
// A staged transposed in LDS [BK][BM+1] (pad kills stride-128 bank conflicts).
// ---------------------------------------------------------------------------
__global__ __launch_bounds__(256) void gemm_kernel(const float* __restrict__ x,
                                                   const float* __restrict__ w,
                                                   float* __restrict__ z, int M) {
    __shared__ float sA[32][129]; // [k][m], padded
    __shared__ float sB[32][128]; // [k][n]

    const int tid = threadIdx.x;
    const int block_row = blockIdx.x * 128;

    const int tx = tid & 15;  // column group -> cols tx*8 .. tx*8+7
    const int ty = tid >> 4;  // row group    -> rows ty*8 .. ty*8+7

    float acc[8][8];
#pragma unroll
    for (int i = 0; i < 8; ++i)
#pragma unroll
        for (int j = 0; j < 8; ++j) acc[i][j] = 0.f;

    // A staging map: 128 rows x 32 k-cols, 4 x float4 per thread
    const int arow = tid >> 3;        // 0..31
    const int acol = (tid & 7) * 4;   // 0,4,...,28
    // B staging map: 32 k-rows x 128 cols, 4 x float4 per thread
    const int brow = tid >> 5;        // 0..7
    const int bcol = (tid & 31) * 4;  // 0,4,...,124

    for (int k0 = 0; k0 < IN_DIM; k0 += 32) {
        // stage A (transposed)
#pragma unroll
        for (int i = 0; i < 4; ++i) {
            const int r = arow + i * 32;
            const int grow = block_row + r;
            float4 v = make_float4(0.f, 0.f, 0.f, 0.f);
            if (grow < M)
                v = *(const float4*)(x + (size_t)grow * IN_DIM + k0 + acol);
            sA[acol + 0][r] = v.x;
            sA[acol + 1][r] = v.y;
            sA[acol + 2][r] = v.z;
            sA[acol + 3][r] = v.w;
        }
        // stage B (natural)
#pragma unroll
        for (int i = 0; i < 4; ++i) {
            const int r = brow + i * 8;
            *(float4*)(&sB[r][bcol]) =
                *(const float4*)(w + (size_t)(k0 + r) * OUT_DIM + bcol);
        }
        __syncthreads();

#pragma unroll
        for (int k = 0; k < 32; ++k) {
            float a[8], b[8];
            *(float4*)&a[0] = *(const float4*)&sA[k][ty * 8];
            *(float4*)&a[4] = *(const float4*)&sA[k][ty * 8 + 4];
            *(float4*)&b[0] = *(const float4*)&sB[k][tx * 8];
            *(float4*)&b[4] = *(const float4*)&sB[k][tx * 8 + 4];
#pragma unroll
            for (int i = 0; i < 8; ++i)
#pragma unroll
                for (int j = 0; j < 8; ++j)
                    acc[i][j] = fmaf(a[i], b[j], acc[i][j]);
        }
        __syncthreads();
    }

#pragma unroll
    for (int i = 0; i < 8; ++i) {
        const int grow = block_row + ty * 8 + i;
        if (grow < M) {
            *(float4*)(z + (size_t)grow * OUT_DIM + tx * 8 + 0) = *(float4*)&acc[i][0];
            *(float4*)(z + (size_t)grow * OUT_DIM + tx * 8 + 4) = *(float4*)&acc[i][4];
        }
    }
}

// ---------------------------------------------------------------------------
// Decode: out[i] = sigmoid( sum_k z[a_i,k]*z[b_i,k]*w3[k] )
// One wave (64 lanes) per edge; lane handles 2 of the 128 features (float2).
// Wave index < E1 -> train_edges, else train_false_edges (matches concat).
// ---------------------------------------------------------------------------
__global__ __launch_bounds__(256) void decode_kernel(const float* __restrict__ z,
                                                     const int* __restrict__ e1,
                                                     const int* __restrict__ e2,
                                                     const float* __restrict__ w3,
                                                     float* __restrict__ out,
                                                     int E1, int E2) {
    const int wave = (int)((blockIdx.x * (size_t)blockDim.x + threadIdx.x) >> 6);
    const int lane = threadIdx.x & 63;
    if (wave >= E1 + E2) return;

    const bool first = (wave < E1);
    const int* e = first ? e1 : e2;
    const int idx = first ? wave : wave - E1;

    const int na = e[2 * idx];
    const int nb = e[2 * idx + 1];

    const float2 za = *(const float2*)(z + (size_t)na * OUT_DIM + lane * 2);
    const float2 zb = *(const float2*)(z + (size_t)nb * OUT_DIM + lane * 2);
    const float2 w  = *(const float2*)(w3 + lane * 2);

    float v = za.x * zb.x * w.x + za.y * zb.y * w.y;

#pragma unroll
    for (int off = 32; off > 0; off >>= 1)
        v += __shfl_xor(v, off);

    if (lane == 0)
        out[wave] = 1.f / (1.f + __expf(-v));
}

extern "C" void kernel_launch(void* const* d_in, const int* in_sizes, int n_in,
                              void* d_out, int out_size, void* d_ws, size_t ws_size,
                              hipStream_t stream) {
    const float* x  = (const float*)d_in[0];
    const int*   e1 = (const int*)d_in[1];
    const int*   e2 = (const int*)d_in[2];
    const float* w  = (const float*)d_in[3];
    const float* w3 = (const float*)d_in[4];

    float* out = (float*)d_out;
    float* z   = (float*)d_ws;  // [M, 128] fp32 = 51.2 MB

    const int M  = in_sizes[0] / IN_DIM;  // 100000
    const int E1 = in_sizes[1] / 2;       // 300000
    const int E2 = in_sizes[2] / 2;       // 300000

    // encode
    gemm_kernel<<<(M + 127) / 128, 256, 0, stream>>>(x, w, z, M);

    // decode both edge sets + sigmoid, in concat order
    const int waves = E1 + E2;
    const int blocks = (waves + 3) / 4;  // 4 waves per 256-thread block
    decode_kernel<<<blocks, 256, 0, stream>>>(z, e1, e2, w3, out, E1, E2);
}

// Round 2
// 209.674 us; speedup vs baseline: 1.5494x; 1.5494x over previous
//
#include <hip/hip_runtime.h>
#include <math.h>

#define IN_DIM 512
#define OUT_DIM 128
#define BM 128
#define BK 64

typedef __attribute__((ext_vector_type(8))) __bf16 bf16x8;
typedef __attribute__((ext_vector_type(4))) float f32x4;

__device__ inline unsigned short f2bf(float f) {
    unsigned u = __float_as_uint(f);
    u += 0x7FFFu + ((u >> 16) & 1u);  // round-to-nearest-even
    return (unsigned short)(u >> 16);
}

// XOR-swizzled byte offset within a [rows][64-bf16] LDS tile (128 B per row).
// Spreads the stride-128B column access of ds_read_b128 across 8 bank slots.
__device__ inline int swz(int row, int kbyte) {
    return row * 128 + (kbyte ^ ((row & 7) << 4));
}

// w [512][128] f32  ->  w_t [128][512] bf16  (one-time, 128 KB, L2-resident)
__global__ void wt_kernel(const float* __restrict__ w, unsigned short* __restrict__ wt) {
    int idx = blockIdx.x * 256 + threadIdx.x;
    int k = idx >> 7;    // 0..511
    int n = idx & 127;   // 0..127
    wt[n * IN_DIM + k] = f2bf(w[idx]);
}

// ---------------------------------------------------------------------------
// z[M,128] = x[M,512] @ w[512,128]  via bf16 MFMA, fp32 accumulate.
// BM=128 rows/block, full N=128, BK=64. 4 waves (2x2), each wave 64x64 out.
// fp32 x is converted to bf16 during LDS staging (fused, no extra HBM pass).
// ---------------------------------------------------------------------------
__global__ __launch_bounds__(256) void gemm_mfma(const float* __restrict__ x,
                                                 const unsigned short* __restrict__ wt,
                                                 float* __restrict__ z, int M) {
    __shared__ unsigned short sA[BM * BK];       // 16 KB, swizzled
    __shared__ unsigned short sB[OUT_DIM * BK];  // 16 KB, swizzled (wt rows)
    char* const pA = (char*)sA;
    char* const pB = (char*)sB;

    const int tid  = threadIdx.x;
    const int lane = tid & 63;
    const int wid  = tid >> 6;
    const int wm   = wid >> 1;   // 0..1 : wave row
    const int wn   = wid & 1;    // 0..1 : wave col
    const int block_row = blockIdx.x * BM;

    f32x4 acc[4][4];
#pragma unroll
    for (int i = 0; i < 4; ++i)
#pragma unroll
        for (int j = 0; j < 4; ++j) acc[i][j] = (f32x4){0.f, 0.f, 0.f, 0.f};

    // A staging map: thread t -> rows (t>>4)+16i (i=0..7), k-bytes (t&15)*8 (4 bf16)
    const int a_m0 = tid >> 4;
    const int a_kb = (tid & 15) * 8;
    // B staging map: thread t -> n-row t>>1, k-half (t&1)*32, 4 chunks of 8 bf16
    const int b_n  = tid >> 1;
    const int b_k  = (tid & 1) * 32;

    // MFMA fragment lane mapping
    const int fr = lane & 15;          // row (A) / col (B) within fragment
    const int fk = (lane >> 4) * 8;    // k-octet base

    for (int k0 = 0; k0 < IN_DIM; k0 += BK) {
        if (k0) __syncthreads();
        // stage A: 128 rows x 64 k, fp32 -> bf16, swizzled
#pragma unroll
        for (int i = 0; i < 8; ++i) {
            const int m = a_m0 + i * 16;
            const int gr = block_row + m;
            float4 v = make_float4(0.f, 0.f, 0.f, 0.f);
            if (gr < M)
                v = *(const float4*)(x + (size_t)gr * IN_DIM + k0 + (a_kb >> 1));
            unsigned lo = (unsigned)f2bf(v.x) | ((unsigned)f2bf(v.y) << 16);
            unsigned hi = (unsigned)f2bf(v.z) | ((unsigned)f2bf(v.w) << 16);
            *(uint2*)(pA + swz(m, a_kb)) = make_uint2(lo, hi);
        }
        // stage B: 128 n-rows x 64 k bf16 from wt (already bf16)
#pragma unroll
        for (int i = 0; i < 4; ++i) {
            const int kk = b_k + i * 8;
            bf16x8 v = *(const bf16x8*)(wt + (size_t)b_n * IN_DIM + k0 + kk);
            *(bf16x8*)(pB + swz(b_n, kk * 2)) = v;
        }
        __syncthreads();

#pragma unroll
        for (int ks = 0; ks < BK; ks += 32) {
            bf16x8 a[4], b[4];
#pragma unroll
            for (int mf = 0; mf < 4; ++mf)
                a[mf] = *(const bf16x8*)(pA + swz(wm * 64 + mf * 16 + fr, (ks + fk) * 2));
#pragma unroll
            for (int nf = 0; nf < 4; ++nf)
                b[nf] = *(const bf16x8*)(pB + swz(wn * 64 + nf * 16 + fr, (ks + fk) * 2));
#pragma unroll
            for (int mf = 0; mf < 4; ++mf)
#pragma unroll
                for (int nf = 0; nf < 4; ++nf)
                    acc[mf][nf] = __builtin_amdgcn_mfma_f32_16x16x32_bf16(
                        a[mf], b[nf], acc[mf][nf], 0, 0, 0);
        }
    }

    // C/D layout: col = lane&15, row = (lane>>4)*4 + reg   [verified m89/m91]
    const int crow0 = (lane >> 4) * 4;
    const int ccol  = lane & 15;
#pragma unroll
    for (int mf = 0; mf < 4; ++mf)
#pragma unroll
        for (int r = 0; r < 4; ++r) {
            const int grow = block_row + wm * 64 + mf * 16 + crow0 + r;
            if (grow < M) {
                float* zr = z + (size_t)grow * OUT_DIM + wn * 64 + ccol;
#pragma unroll
                for (int nf = 0; nf < 4; ++nf)
                    zr[nf * 16] = acc[mf][nf][r];
            }
        }
}

// ---------------------------------------------------------------------------
// Decode: out[i] = sigmoid( sum_k z[a_i,k]*z[b_i,k]*w3[k] )
// One wave per edge; lane handles 2 of 128 features.
// ---------------------------------------------------------------------------
__global__ __launch_bounds__(256) void decode_kernel(const float* __restrict__ z,
                                                     const int* __restrict__ e1,
                                                     const int* __restrict__ e2,
                                                     const float* __restrict__ w3,
                                                     float* __restrict__ out,
                                                     int E1, int E2) {
    const int wave = (int)((blockIdx.x * (size_t)blockDim.x + threadIdx.x) >> 6);
    const int lane = threadIdx.x & 63;
    if (wave >= E1 + E2) return;

    const bool first = (wave < E1);
    const int* e = first ? e1 : e2;
    const int idx = first ? wave : wave - E1;

    const int na = e[2 * idx];
    const int nb = e[2 * idx + 1];

    const float2 za = *(const float2*)(z + (size_t)na * OUT_DIM + lane * 2);
    const float2 zb = *(const float2*)(z + (size_t)nb * OUT_DIM + lane * 2);
    const float2 w  = *(const float2*)(w3 + lane * 2);

    float v = za.x * zb.x * w.x + za.y * zb.y * w.y;

#pragma unroll
    for (int off = 32; off > 0; off >>= 1)
        v += __shfl_xor(v, off);

    if (lane == 0)
        out[wave] = 1.f / (1.f + __expf(-v));
}

extern "C" void kernel_launch(void* const* d_in, const int* in_sizes, int n_in,
                              void* d_out, int out_size, void* d_ws, size_t ws_size,
                              hipStream_t stream) {
    const float* x  = (const float*)d_in[0];
    const int*   e1 = (const int*)d_in[1];
    const int*   e2 = (const int*)d_in[2];
    const float* w  = (const float*)d_in[3];
    const float* w3 = (const float*)d_in[4];

    float* out = (float*)d_out;

    const int M  = in_sizes[0] / IN_DIM;  // 100000
    const int E1 = in_sizes[1] / 2;       // 300000
    const int E2 = in_sizes[2] / 2;       // 300000

    // workspace layout: z [M,128] fp32 (51.2 MB), then w_t [128][512] bf16 (128 KB)
    float* z = (float*)d_ws;
    unsigned short* wt = (unsigned short*)((char*)d_ws + (size_t)M * OUT_DIM * sizeof(float));

    // 1) transpose+convert w -> w_t (bf16)
    wt_kernel<<<(IN_DIM * OUT_DIM) / 256, 256, 0, stream>>>(w, wt);

    // 2) encode GEMM (bf16 MFMA)
    gemm_mfma<<<(M + BM - 1) / BM, 256, 0, stream>>>(x, wt, z, M);

    // 3) decode both edge sets + sigmoid, in concat order
    const int waves = E1 + E2;
    const int blocks = (waves + 3) / 4;
    decode_kernel<<<blocks, 256, 0, stream>>>(z, e1, e2, w3, out, E1, E2);
}

// Round 3
// 143.654 us; speedup vs baseline: 2.2615x; 1.4596x over previous
//
#include <hip/hip_runtime.h>
#include <math.h>

#define IN_DIM 512
#define OUT_DIM 128
#define BM 64
#define BK 64
#define NKT (IN_DIM / BK)  // 8

typedef __attribute__((ext_vector_type(8))) __bf16 bf16x8;
typedef __attribute__((ext_vector_type(4))) float f32x4;

__device__ inline unsigned short f2bf(float f) {
    unsigned u = __float_as_uint(f);
    u += 0x7FFFu + ((u >> 16) & 1u);  // round-to-nearest-even
    return (unsigned short)(u >> 16);
}
__device__ inline unsigned pack2(float a, float b) {
    return (unsigned)f2bf(a) | ((unsigned)f2bf(b) << 16);
}

// XOR-swizzled byte offset within a [rows][64-bf16] LDS tile (128 B per row).
__device__ inline int swz(int row, int kbyte) {
    return row * 128 + (kbyte ^ ((row & 7) << 4));
}

// w [512][128] f32 -> w_t [128][512] bf16 (one-time, 128 KB, L2-resident)
__global__ void wt_kernel(const float* __restrict__ w, unsigned short* __restrict__ wt) {
    int idx = blockIdx.x * 256 + threadIdx.x;
    int k = idx >> 7;
    int n = idx & 127;
    wt[n * IN_DIM + k] = f2bf(w[idx]);
}

// ---------------------------------------------------------------------------
// z[M,128] = x[M,512] @ w[512,128] via bf16 MFMA, fp32 accumulate.
// BM=64, BK=64, 4 waves (2x2), each wave 32x64. 1-deep register prefetch:
// next tile's global loads issue right after the barrier, hiding HBM latency
// under the ds_read+MFMA phase.
// ---------------------------------------------------------------------------
__global__ __launch_bounds__(256, 4) void gemm_mfma(const float* __restrict__ x,
                                                    const unsigned short* __restrict__ wt,
                                                    float* __restrict__ z, int M) {
    __shared__ unsigned short sA[BM * BK];       // 8 KB, swizzled
    __shared__ unsigned short sB[OUT_DIM * BK];  // 16 KB, swizzled
    char* const pA = (char*)sA;
    char* const pB = (char*)sB;

    const int tid  = threadIdx.x;
    const int lane = tid & 63;
    const int wid  = tid >> 6;
    const int wm   = wid >> 1;  // 0..1
    const int wn   = wid & 1;   // 0..1
    const int block_row = blockIdx.x * BM;

    f32x4 acc[2][4];
#pragma unroll
    for (int i = 0; i < 2; ++i)
#pragma unroll
        for (int j = 0; j < 4; ++j) acc[i][j] = (f32x4){0.f, 0.f, 0.f, 0.f};

    // A staging: thread t -> row t>>2 (0..63), fp32 cols (t&3)*16 .. +16
    const int a_row = tid >> 2;
    const int a_col = (tid & 3) * 16;
    const bool a_ok = (block_row + a_row) < M;
    const float* xp = x + (size_t)(block_row + a_row) * IN_DIM + a_col;
    const int a_b0 = swz(a_row, a_col * 2);
    const int a_b1 = swz(a_row, a_col * 2 + 16);

    // B staging: thread t -> n-row t>>1 (0..127), k-half (t&1)*32
    const int b_row = tid >> 1;
    const int b_col = (tid & 1) * 32;
    const unsigned short* wp = wt + (size_t)b_row * IN_DIM + b_col;
    int b_off[4];
#pragma unroll
    for (int i = 0; i < 4; ++i) b_off[i] = swz(b_row, b_col * 2 + 16 * i);

    // MFMA fragment lane mapping
    const int fr  = lane & 15;
    const int fkb = (lane >> 4) * 16;  // k byte offset

    float4 ra[4];
    bf16x8 rb[4];
    const float4 z4 = make_float4(0.f, 0.f, 0.f, 0.f);

    // prologue: load tile 0
#pragma unroll
    for (int i = 0; i < 4; ++i) ra[i] = a_ok ? *(const float4*)(xp + 4 * i) : z4;
#pragma unroll
    for (int i = 0; i < 4; ++i) rb[i] = *(const bf16x8*)(wp + 8 * i);

#pragma unroll
    for (int kt = 0; kt < NKT; ++kt) {
        if (kt) __syncthreads();  // prev MFMA done reading LDS
        // store staged tile (regs -> LDS, fp32->bf16 for A)
        uint4 u0, u1;
        u0.x = pack2(ra[0].x, ra[0].y); u0.y = pack2(ra[0].z, ra[0].w);
        u0.z = pack2(ra[1].x, ra[1].y); u0.w = pack2(ra[1].z, ra[1].w);
        u1.x = pack2(ra[2].x, ra[2].y); u1.y = pack2(ra[2].z, ra[2].w);
        u1.z = pack2(ra[3].x, ra[3].y); u1.w = pack2(ra[3].z, ra[3].w);
        *(uint4*)(pA + a_b0) = u0;
        *(uint4*)(pA + a_b1) = u1;
#pragma unroll
        for (int i = 0; i < 4; ++i) *(bf16x8*)(pB + b_off[i]) = rb[i];
        __syncthreads();

        // issue next tile's global loads (overlap with MFMA below)
        if (kt + 1 < NKT) {
            const int k0 = (kt + 1) * BK;
#pragma unroll
            for (int i = 0; i < 4; ++i)
                ra[i] = a_ok ? *(const float4*)(xp + k0 + 4 * i) : z4;
#pragma unroll
            for (int i = 0; i < 4; ++i) rb[i] = *(const bf16x8*)(wp + k0 + 8 * i);
        }

        // MFMA phase on current LDS tile
#pragma unroll
        for (int ks = 0; ks < 2; ++ks) {
            bf16x8 af[2], bfv[4];
#pragma unroll
            for (int mf = 0; mf < 2; ++mf)
                af[mf] = *(const bf16x8*)(pA + swz(wm * 32 + mf * 16 + fr, ks * 64 + fkb));
#pragma unroll
            for (int nf = 0; nf < 4; ++nf)
                bfv[nf] = *(const bf16x8*)(pB + swz(wn * 64 + nf * 16 + fr, ks * 64 + fkb));
#pragma unroll
            for (int mf = 0; mf < 2; ++mf)
#pragma unroll
                for (int nf = 0; nf < 4; ++nf)
                    acc[mf][nf] = __builtin_amdgcn_mfma_f32_16x16x32_bf16(
                        af[mf], bfv[nf], acc[mf][nf], 0, 0, 0);
        }
    }

    // C/D layout: col = lane&15, row = (lane>>4)*4 + reg
    const int crow0 = (lane >> 4) * 4;
    const int ccol  = lane & 15;
#pragma unroll
    for (int mf = 0; mf < 2; ++mf)
#pragma unroll
        for (int r = 0; r < 4; ++r) {
            const int grow = block_row + wm * 32 + mf * 16 + crow0 + r;
            if (grow < M) {
                float* zr = z + (size_t)grow * OUT_DIM + wn * 64 + ccol;
#pragma unroll
                for (int nf = 0; nf < 4; ++nf)
                    zr[nf * 16] = acc[mf][nf][r];
            }
        }
}

// ---------------------------------------------------------------------------
// Decode: out[e] = sigmoid( sum_k z[a_e,k]*z[b_e,k]*w3[k] )
// 16 lanes per edge, 4 edges per wave, grid-stride. w3 hoisted to registers.
// ---------------------------------------------------------------------------
__global__ __launch_bounds__(256) void decode_kernel(const float* __restrict__ z,
                                                     const int* __restrict__ e1,
                                                     const int* __restrict__ e2,
                                                     const float* __restrict__ w3,
                                                     float* __restrict__ out,
                                                     int E1, int E2) {
    const int tid  = threadIdx.x;
    const int lane = tid & 63;
    const int sub  = lane & 15;   // lane within 16-group
    const int sg   = lane >> 4;   // edge slot within wave (0..3)
    const int Etot = E1 + E2;
    const int nquads = (Etot + 3) >> 2;

    const float4 w3a = *(const float4*)(w3 + sub * 4);
    const float4 w3b = *(const float4*)(w3 + 64 + sub * 4);

    const int wave_global = blockIdx.x * 4 + (tid >> 6);
    const int nwaves = gridDim.x * 4;

    for (int q = wave_global; q < nquads; q += nwaves) {
        const int e = q * 4 + sg;
        if (e < Etot) {
            int2 ab;
            if (e < E1) ab = ((const int2*)e1)[e];
            else        ab = ((const int2*)e2)[e - E1];

            const float* za = z + (size_t)ab.x * OUT_DIM;
            const float* zb = z + (size_t)ab.y * OUT_DIM;
            const float4 a0 = *(const float4*)(za + sub * 4);
            const float4 a1 = *(const float4*)(za + 64 + sub * 4);
            const float4 b0 = *(const float4*)(zb + sub * 4);
            const float4 b1 = *(const float4*)(zb + 64 + sub * 4);

            float v = a0.x * b0.x * w3a.x;
            v = fmaf(a0.y, b0.y * w3a.y, v);
            v = fmaf(a0.z, b0.z * w3a.z, v);
            v = fmaf(a0.w, b0.w * w3a.w, v);
            v = fmaf(a1.x, b1.x * w3b.x, v);
            v = fmaf(a1.y, b1.y * w3b.y, v);
            v = fmaf(a1.z, b1.z * w3b.z, v);
            v = fmaf(a1.w, b1.w * w3b.w, v);

            v += __shfl_xor(v, 8);
            v += __shfl_xor(v, 4);
            v += __shfl_xor(v, 2);
            v += __shfl_xor(v, 1);

            if (sub == 0) out[e] = 1.f / (1.f + __expf(-v));
        }
    }
}

extern "C" void kernel_launch(void* const* d_in, const int* in_sizes, int n_in,
                              void* d_out, int out_size, void* d_ws, size_t ws_size,
                              hipStream_t stream) {
    const float* x  = (const float*)d_in[0];
    const int*   e1 = (const int*)d_in[1];
    const int*   e2 = (const int*)d_in[2];
    const float* w  = (const float*)d_in[3];
    const float* w3 = (const float*)d_in[4];

    float* out = (float*)d_out;

    const int M  = in_sizes[0] / IN_DIM;  // 100000
    const int E1 = in_sizes[1] / 2;       // 300000
    const int E2 = in_sizes[2] / 2;       // 300000

    float* z = (float*)d_ws;  // [M,128] fp32 = 51.2 MB
    unsigned short* wt = (unsigned short*)((char*)d_ws + (size_t)M * OUT_DIM * sizeof(float));

    wt_kernel<<<(IN_DIM * OUT_DIM) / 256, 256, 0, stream>>>(w, wt);
    gemm_mfma<<<(M + BM - 1) / BM, 256, 0, stream>>>(x, wt, z, M);
    decode_kernel<<<4096, 256, 0, stream>>>(z, e1, e2, w3, out, E1, E2);
}

// Round 4
// 102.696 us; speedup vs baseline: 3.1635x; 1.3988x over previous
//
#include <hip/hip_runtime.h>
#include <math.h>

#define IN_DIM 512
#define OUT_DIM 128
#define BM 64
#define BK 64
#define NKT (IN_DIM / BK)  // 8

typedef __attribute__((ext_vector_type(8))) __bf16 bf16x8;
typedef __attribute__((ext_vector_type(4))) float f32x4;

__device__ inline unsigned short f2bf(float f) {
    unsigned u = __float_as_uint(f);
    u += 0x7FFFu + ((u >> 16) & 1u);  // round-to-nearest-even
    return (unsigned short)(u >> 16);
}
__device__ inline float bf2f(unsigned short h) {
    return __uint_as_float((unsigned)h << 16);
}
__device__ inline unsigned pack2(unsigned short a, unsigned short b) {
    return (unsigned)a | ((unsigned)b << 16);
}

// XOR-swizzled byte offset within a [rows][64-bf16] LDS tile (128 B per row).
__device__ inline int swz(int row, int kbyte) {
    return row * 128 + (kbyte ^ ((row & 7) << 4));
}

// w [512][128] f32 -> wt2 k-interleaved bf16: wt2[(k>>3)*128 + n][k&7]
// so a wave's B-fragment load (16 consecutive n, same k-octet) is contiguous.
__global__ void wt2_kernel(const float* __restrict__ w, unsigned short* __restrict__ wt2) {
    int idx = blockIdx.x * 256 + threadIdx.x;  // 65536 total
    int k = idx >> 7;
    int n = idx & 127;
    wt2[(((k >> 3) * 128) + n) * 8 + (k & 7)] = f2bf(w[idx]);
}

// ---------------------------------------------------------------------------
// z_bf[M,128](bf16) = x[M,512] @ w[512,128] via bf16 MFMA, fp32 accumulate.
// Split-bf16 A (a = a_hi + a_lo, 2 MFMAs) -> fp32-class GEMM accuracy, so the
// only z error is its bf16 storage quantization.
// B fragments read directly from L2-resident wt2 (no LDS). LDS = A hi/lo only.
// 4 waves (2x2), each wave 32x64 out. 1-deep register prefetch on A.
// ---------------------------------------------------------------------------
__global__ __launch_bounds__(256, 4) void gemm_mfma(const float* __restrict__ x,
                                                    const unsigned short* __restrict__ wt2,
                                                    unsigned short* __restrict__ zb,
                                                    int M) {
    __shared__ unsigned short sAh[BM * BK];  // 8 KB, swizzled
    __shared__ unsigned short sAl[BM * BK];  // 8 KB, swizzled
    char* const pAh = (char*)sAh;
    char* const pAl = (char*)sAl;

    const int tid  = threadIdx.x;
    const int lane = tid & 63;
    const int wid  = tid >> 6;
    const int wm   = wid >> 1;  // 0..1
    const int wn   = wid & 1;   // 0..1
    const int block_row = blockIdx.x * BM;

    f32x4 acc[2][4];
#pragma unroll
    for (int i = 0; i < 2; ++i)
#pragma unroll
        for (int j = 0; j < 4; ++j) acc[i][j] = (f32x4){0.f, 0.f, 0.f, 0.f};

    // A staging: thread t -> row t>>2 (0..63), fp32 cols (t&3)*16 .. +16
    const int a_row = tid >> 2;
    const int a_col = (tid & 3) * 16;
    const bool a_ok = (block_row + a_row) < M;
    const float* xp = x + (size_t)(block_row + a_row) * IN_DIM + a_col;
    const int a_b0 = swz(a_row, a_col * 2);
    const int a_b1 = swz(a_row, a_col * 2 + 16);

    // MFMA fragment lane mapping
    const int fr  = lane & 15;
    const int fk4 = lane >> 4;            // k-octet group 0..3
    const int fkb = fk4 * 16;             // k byte offset in LDS row

    // B fragment base in wt2 (element units)
    const unsigned short* wtb = wt2 + (size_t)fk4 * 1024 + (wn * 64 + fr) * 8;

    float4 ra[4];
    const float4 z4 = make_float4(0.f, 0.f, 0.f, 0.f);

    // prologue: load x tile 0
#pragma unroll
    for (int i = 0; i < 4; ++i) ra[i] = a_ok ? *(const float4*)(xp + 4 * i) : z4;

#pragma unroll
    for (int kt = 0; kt < NKT; ++kt) {
        if (kt) __syncthreads();
        // split fp32 -> bf16 hi/lo and store to LDS
        unsigned short h[16], l[16];
        const float* rf = (const float*)ra;
#pragma unroll
        for (int i = 0; i < 16; ++i) {
            h[i] = f2bf(rf[i]);
            l[i] = f2bf(rf[i] - bf2f(h[i]));
        }
        uint4 uh0, uh1, ul0, ul1;
        uh0.x = pack2(h[0], h[1]);  uh0.y = pack2(h[2], h[3]);
        uh0.z = pack2(h[4], h[5]);  uh0.w = pack2(h[6], h[7]);
        uh1.x = pack2(h[8], h[9]);  uh1.y = pack2(h[10], h[11]);
        uh1.z = pack2(h[12], h[13]); uh1.w = pack2(h[14], h[15]);
        ul0.x = pack2(l[0], l[1]);  ul0.y = pack2(l[2], l[3]);
        ul0.z = pack2(l[4], l[5]);  ul0.w = pack2(l[6], l[7]);
        ul1.x = pack2(l[8], l[9]);  ul1.y = pack2(l[10], l[11]);
        ul1.z = pack2(l[12], l[13]); ul1.w = pack2(l[14], l[15]);
        *(uint4*)(pAh + a_b0) = uh0;
        *(uint4*)(pAh + a_b1) = uh1;
        *(uint4*)(pAl + a_b0) = ul0;
        *(uint4*)(pAl + a_b1) = ul1;
        __syncthreads();

        // prefetch next x tile (overlaps with MFMA below)
        if (kt + 1 < NKT) {
            const int k0 = (kt + 1) * BK;
#pragma unroll
            for (int i = 0; i < 4; ++i)
                ra[i] = a_ok ? *(const float4*)(xp + k0 + 4 * i) : z4;
        }

        // MFMA phase: A from LDS, B from L2-resident wt2
#pragma unroll
        for (int ks = 0; ks < 2; ++ks) {
            bf16x8 ah[2], al[2], bv[4];
#pragma unroll
            for (int mf = 0; mf < 2; ++mf) {
                ah[mf] = *(const bf16x8*)(pAh + swz(wm * 32 + mf * 16 + fr, ks * 64 + fkb));
                al[mf] = *(const bf16x8*)(pAl + swz(wm * 32 + mf * 16 + fr, ks * 64 + fkb));
            }
#pragma unroll
            for (int nf = 0; nf < 4; ++nf)
                bv[nf] = *(const bf16x8*)(wtb + kt * 8192 + ks * 4096 + nf * 128);
#pragma unroll
            for (int mf = 0; mf < 2; ++mf)
#pragma unroll
                for (int nf = 0; nf < 4; ++nf) {
                    acc[mf][nf] = __builtin_amdgcn_mfma_f32_16x16x32_bf16(
                        ah[mf], bv[nf], acc[mf][nf], 0, 0, 0);
                    acc[mf][nf] = __builtin_amdgcn_mfma_f32_16x16x32_bf16(
                        al[mf], bv[nf], acc[mf][nf], 0, 0, 0);
                }
        }
    }

    // C/D layout: col = lane&15, row = (lane>>4)*4 + reg. Store bf16.
    const int crow0 = (lane >> 4) * 4;
    const int ccol  = lane & 15;
#pragma unroll
    for (int mf = 0; mf < 2; ++mf)
#pragma unroll
        for (int r = 0; r < 4; ++r) {
            const int grow = block_row + wm * 32 + mf * 16 + crow0 + r;
            if (grow < M) {
                unsigned short* zr = zb + (size_t)grow * OUT_DIM + wn * 64 + ccol;
#pragma unroll
                for (int nf = 0; nf < 4; ++nf)
                    zr[nf * 16] = f2bf(acc[mf][nf][r]);
            }
        }
}

// ---------------------------------------------------------------------------
// Decode: out[e] = sigmoid( sum_k z[a_e,k]*z[b_e,k]*w3[k] ), z in bf16.
// 16 lanes per edge, 4 edges per wave, grid-stride. One bf16x8 load per row
// per lane (exactly the row bytes). w3 hoisted to registers (f32).
// ---------------------------------------------------------------------------
__global__ __launch_bounds__(256) void decode_kernel(const unsigned short* __restrict__ zb,
                                                     const int* __restrict__ e1,
                                                     const int* __restrict__ e2,
                                                     const float* __restrict__ w3,
                                                     float* __restrict__ out,
                                                     int E1, int E2) {
    const int tid  = threadIdx.x;
    const int lane = tid & 63;
    const int sub  = lane & 15;   // lane within 16-group
    const int sg   = lane >> 4;   // edge slot within wave (0..3)
    const int Etot = E1 + E2;
    const int nquads = (Etot + 3) >> 2;

    float w3r[8];
    *(float4*)&w3r[0] = *(const float4*)(w3 + sub * 8);
    *(float4*)&w3r[4] = *(const float4*)(w3 + sub * 8 + 4);

    const int wave_global = blockIdx.x * 4 + (tid >> 6);
    const int nwaves = gridDim.x * 4;

    for (int q = wave_global; q < nquads; q += nwaves) {
        const int e = q * 4 + sg;
        if (e < Etot) {
            int2 ab;
            if (e < E1) ab = ((const int2*)e1)[e];
            else        ab = ((const int2*)e2)[e - E1];

            const uint4 ua = *(const uint4*)(zb + (size_t)ab.x * OUT_DIM + sub * 8);
            const uint4 ub = *(const uint4*)(zb + (size_t)ab.y * OUT_DIM + sub * 8);
            const unsigned pa[4] = {ua.x, ua.y, ua.z, ua.w};
            const unsigned pb[4] = {ub.x, ub.y, ub.z, ub.w};

            float v = 0.f;
#pragma unroll
            for (int i = 0; i < 4; ++i) {
                const float a0 = __uint_as_float(pa[i] << 16);
                const float a1 = __uint_as_float(pa[i] & 0xFFFF0000u);
                const float b0 = __uint_as_float(pb[i] << 16);
                const float b1 = __uint_as_float(pb[i] & 0xFFFF0000u);
                v = fmaf(a0 * b0, w3r[2 * i], v);
                v = fmaf(a1 * b1, w3r[2 * i + 1], v);
            }

            v += __shfl_xor(v, 8);
            v += __shfl_xor(v, 4);
            v += __shfl_xor(v, 2);
            v += __shfl_xor(v, 1);

            if (sub == 0) out[e] = 1.f / (1.f + __expf(-v));
        }
    }
}

extern "C" void kernel_launch(void* const* d_in, const int* in_sizes, int n_in,
                              void* d_out, int out_size, void* d_ws, size_t ws_size,
                              hipStream_t stream) {
    const float* x  = (const float*)d_in[0];
    const int*   e1 = (const int*)d_in[1];
    const int*   e2 = (const int*)d_in[2];
    const float* w  = (const float*)d_in[3];
    const float* w3 = (const float*)d_in[4];

    float* out = (float*)d_out;

    const int M  = in_sizes[0] / IN_DIM;  // 100000
    const int E1 = in_sizes[1] / 2;       // 300000
    const int E2 = in_sizes[2] / 2;       // 300000

    // workspace: z_bf [M,128] bf16 (25.6 MB), then wt2 [512x128] bf16 (128 KB)
    unsigned short* zbuf = (unsigned short*)d_ws;
    unsigned short* wt2  = zbuf + (size_t)M * OUT_DIM;

    wt2_kernel<<<(IN_DIM * OUT_DIM) / 256, 256, 0, stream>>>(w, wt2);
    gemm_mfma<<<(M + BM - 1) / BM, 256, 0, stream>>>(x, wt2, zbuf, M);
    decode_kernel<<<4096, 256, 0, stream>>>(zbuf, e1, e2, w3, out, E1, E2);
}

// Round 5
// 100.333 us; speedup vs baseline: 3.2380x; 1.0236x over previous
//
#include <hip/hip_runtime.h>
#include <math.h>

#define IN_DIM 512
#define OUT_DIM 128
#define BM 64
#define BK 64
#define NKT (IN_DIM / BK)  // 8

typedef __attribute__((ext_vector_type(8))) __bf16 bf16x8;
typedef __attribute__((ext_vector_type(4))) float f32x4;
typedef __attribute__((ext_vector_type(2))) float f32x2;

__device__ inline unsigned short f2bf(float f) {
    unsigned u = __float_as_uint(f);
    u += 0x7FFFu + ((u >> 16) & 1u);  // round-to-nearest-even
    return (unsigned short)(u >> 16);
}
__device__ inline unsigned pack2f(float a, float b) {
    return (unsigned)f2bf(a) | ((unsigned)f2bf(b) << 16);
}

// XOR-swizzled byte offset within a [rows][64-bf16] LDS tile (128 B per row).
__device__ inline int swz(int row, int kbyte) {
    return row * 128 + (kbyte ^ ((row & 7) << 4));
}

// w [512][128] f32 -> wt2 k-interleaved bf16: wt2[(k>>3)*128 + n][k&7]
// so a wave's B-fragment load (16 consecutive n, same k-octet) is contiguous.
__global__ void wt2_kernel(const float* __restrict__ w, unsigned short* __restrict__ wt2) {
    int idx = blockIdx.x * 256 + threadIdx.x;  // 65536 total
    int k = idx >> 7;
    int n = idx & 127;
    wt2[(((k >> 3) * 128) + n) * 8 + (k & 7)] = f2bf(w[idx]);
}

// ---------------------------------------------------------------------------
// z_bf[M,128](bf16) = x[M,512] @ w[512,128] via bf16 MFMA, fp32 accumulate.
// A converted fp32->bf16 during LDS staging (8 KB, swizzled). B fragments read
// directly from L2-resident wt2 (no LDS for B). 4 waves (2x2), wave = 32x64.
// 1-deep register prefetch on A. 6 blocks/CU for latency hiding.
// ---------------------------------------------------------------------------
__global__ __launch_bounds__(256, 6) void gemm_mfma(const float* __restrict__ x,
                                                    const unsigned short* __restrict__ wt2,
                                                    unsigned short* __restrict__ zb,
                                                    int M) {
    __shared__ unsigned short sA[BM * BK];  // 8 KB, swizzled
    char* const pA = (char*)sA;

    const int tid  = threadIdx.x;
    const int lane = tid & 63;
    const int wid  = tid >> 6;
    const int wm   = wid >> 1;  // 0..1
    const int wn   = wid & 1;   // 0..1
    const int block_row = blockIdx.x * BM;

    f32x4 acc[2][4];
#pragma unroll
    for (int i = 0; i < 2; ++i)
#pragma unroll
        for (int j = 0; j < 4; ++j) acc[i][j] = (f32x4){0.f, 0.f, 0.f, 0.f};

    // A staging: thread t -> row t>>2 (0..63), fp32 cols (t&3)*16 .. +16
    const int a_row = tid >> 2;
    const int a_col = (tid & 3) * 16;
    const bool a_ok = (block_row + a_row) < M;
    const float* xp = x + (size_t)(block_row + a_row) * IN_DIM + a_col;
    const int a_b0 = swz(a_row, a_col * 2);
    const int a_b1 = swz(a_row, a_col * 2 + 16);

    // MFMA fragment lane mapping
    const int fr  = lane & 15;
    const int fk4 = lane >> 4;  // k-octet group 0..3
    const int fkb = fk4 * 16;   // k byte offset in LDS row

    // B fragment base in wt2 (element units)
    const unsigned short* wtb = wt2 + (size_t)fk4 * 1024 + (wn * 64 + fr) * 8;

    float4 ra[4];
    const float4 z4 = make_float4(0.f, 0.f, 0.f, 0.f);

    // prologue: load x tile 0
#pragma unroll
    for (int i = 0; i < 4; ++i) ra[i] = a_ok ? *(const float4*)(xp + 4 * i) : z4;

#pragma unroll
    for (int kt = 0; kt < NKT; ++kt) {
        if (kt) __syncthreads();
        // fp32 -> bf16 pack and store to LDS
        const float* rf = (const float*)ra;
        uint4 u0, u1;
        u0.x = pack2f(rf[0], rf[1]);   u0.y = pack2f(rf[2], rf[3]);
        u0.z = pack2f(rf[4], rf[5]);   u0.w = pack2f(rf[6], rf[7]);
        u1.x = pack2f(rf[8], rf[9]);   u1.y = pack2f(rf[10], rf[11]);
        u1.z = pack2f(rf[12], rf[13]); u1.w = pack2f(rf[14], rf[15]);
        *(uint4*)(pA + a_b0) = u0;
        *(uint4*)(pA + a_b1) = u1;
        __syncthreads();

        // prefetch next x tile (overlaps with MFMA below)
        if (kt + 1 < NKT) {
            const int k0 = (kt + 1) * BK;
#pragma unroll
            for (int i = 0; i < 4; ++i)
                ra[i] = a_ok ? *(const float4*)(xp + k0 + 4 * i) : z4;
        }

        // MFMA phase: A from LDS, B from L2-resident wt2
#pragma unroll
        for (int ks = 0; ks < 2; ++ks) {
            bf16x8 af[2], bv[4];
#pragma unroll
            for (int mf = 0; mf < 2; ++mf)
                af[mf] = *(const bf16x8*)(pA + swz(wm * 32 + mf * 16 + fr, ks * 64 + fkb));
#pragma unroll
            for (int nf = 0; nf < 4; ++nf)
                bv[nf] = *(const bf16x8*)(wtb + kt * 8192 + ks * 4096 + nf * 128);
#pragma unroll
            for (int mf = 0; mf < 2; ++mf)
#pragma unroll
                for (int nf = 0; nf < 4; ++nf)
                    acc[mf][nf] = __builtin_amdgcn_mfma_f32_16x16x32_bf16(
                        af[mf], bv[nf], acc[mf][nf], 0, 0, 0);
        }
    }

    // C/D layout: col = lane&15, row = (lane>>4)*4 + reg. Store bf16.
    const int crow0 = (lane >> 4) * 4;
    const int ccol  = lane & 15;
#pragma unroll
    for (int mf = 0; mf < 2; ++mf)
#pragma unroll
        for (int r = 0; r < 4; ++r) {
            const int grow = block_row + wm * 32 + mf * 16 + crow0 + r;
            if (grow < M) {
                unsigned short* zr = zb + (size_t)grow * OUT_DIM + wn * 64 + ccol;
#pragma unroll
                for (int nf = 0; nf < 4; ++nf)
                    zr[nf * 16] = f2bf(acc[mf][nf][r]);
            }
        }
}

// ---------------------------------------------------------------------------
// Decode: out[e] = sigmoid( sum_k z[a_e,k]*z[b_e,k]*w3[k] ), z in bf16.
// 16 lanes per edge, 4 edges per wave, grid-stride. Packed f32x2 math
// (v_pk_mul_f32 / v_pk_fma_f32). w3 hoisted to registers.
// ---------------------------------------------------------------------------
__global__ __launch_bounds__(256) void decode_kernel(const unsigned short* __restrict__ zb,
                                                     const int* __restrict__ e1,
                                                     const int* __restrict__ e2,
                                                     const float* __restrict__ w3,
                                                     float* __restrict__ out,
                                                     int E1, int E2) {
    const int tid  = threadIdx.x;
    const int lane = tid & 63;
    const int sub  = lane & 15;   // lane within 16-group
    const int sg   = lane >> 4;   // edge slot within wave (0..3)
    const int Etot = E1 + E2;
    const int nquads = (Etot + 3) >> 2;

    f32x2 w3v[4];
    {
        const float4 wlo = *(const float4*)(w3 + sub * 8);
        const float4 whi = *(const float4*)(w3 + sub * 8 + 4);
        w3v[0] = (f32x2){wlo.x, wlo.y};
        w3v[1] = (f32x2){wlo.z, wlo.w};
        w3v[2] = (f32x2){whi.x, whi.y};
        w3v[3] = (f32x2){whi.z, whi.w};
    }

    const int wave_global = blockIdx.x * 4 + (tid >> 6);
    const int nwaves = gridDim.x * 4;

    for (int q = wave_global; q < nquads; q += nwaves) {
        const int e = q * 4 + sg;
        if (e < Etot) {
            int2 ab;
            if (e < E1) ab = ((const int2*)e1)[e];
            else        ab = ((const int2*)e2)[e - E1];

            const uint4 ua = *(const uint4*)(zb + (size_t)ab.x * OUT_DIM + sub * 8);
            const uint4 ub = *(const uint4*)(zb + (size_t)ab.y * OUT_DIM + sub * 8);
            const unsigned pa[4] = {ua.x, ua.y, ua.z, ua.w};
            const unsigned pb[4] = {ub.x, ub.y, ub.z, ub.w};

            f32x2 vv = (f32x2){0.f, 0.f};
#pragma unroll
            for (int i = 0; i < 4; ++i) {
                f32x2 A = (f32x2){__uint_as_float(pa[i] << 16),
                                  __uint_as_float(pa[i] & 0xFFFF0000u)};
                f32x2 B = (f32x2){__uint_as_float(pb[i] << 16),
                                  __uint_as_float(pb[i] & 0xFFFF0000u)};
                vv += (A * B) * w3v[i];  // v_pk_mul_f32 + v_pk_fma_f32
            }
            float v = vv.x + vv.y;

            v += __shfl_xor(v, 8);
            v += __shfl_xor(v, 4);
            v += __shfl_xor(v, 2);
            v += __shfl_xor(v, 1);

            if (sub == 0) out[e] = 1.f / (1.f + __expf(-v));
        }
    }
}

extern "C" void kernel_launch(void* const* d_in, const int* in_sizes, int n_in,
                              void* d_out, int out_size, void* d_ws, size_t ws_size,
                              hipStream_t stream) {
    const float* x  = (const float*)d_in[0];
    const int*   e1 = (const int*)d_in[1];
    const int*   e2 = (const int*)d_in[2];
    const float* w  = (const float*)d_in[3];
    const float* w3 = (const float*)d_in[4];

    float* out = (float*)d_out;

    const int M  = in_sizes[0] / IN_DIM;  // 100000
    const int E1 = in_sizes[1] / 2;       // 300000
    const int E2 = in_sizes[2] / 2;       // 300000

    // workspace: z_bf [M,128] bf16 (25.6 MB), then wt2 [512x128] bf16 (128 KB)
    unsigned short* zbuf = (unsigned short*)d_ws;
    unsigned short* wt2  = zbuf + (size_t)M * OUT_DIM;

    wt2_kernel<<<(IN_DIM * OUT_DIM) / 256, 256, 0, stream>>>(w, wt2);
    gemm_mfma<<<(M + BM - 1) / BM, 256, 0, stream>>>(x, wt2, zbuf, M);
    decode_kernel<<<4096, 256, 0, stream>>>(zbuf, e1, e2, w3, out, E1, E2);
}